// Round 8
// baseline (179.707 us; speedup 1.0000x reference)
//
#include <hip/hip_runtime.h>
#include <math.h>

#define B_ 512
#define N_ 120

typedef __attribute__((ext_vector_type(8))) _Float16 f16x8;
typedef __attribute__((ext_vector_type(2))) _Float16 f16x2;
typedef __attribute__((ext_vector_type(4))) float f32x4;

// LDS union buffer offsets (f16 units):
//  phase A (setup..stage2): Wq 0 | Wk 4096 | Wv 8192 | T 12288 | xf 16384..24576
//  phase B (scan):          q_s 0 | k_s 7680 | v_s 15360 | o_f 23040..31232
//  persistent:              Wo 31232..35328
#define OFF_WQ 0
#define OFF_WK 4096
#define OFF_WV 8192
#define OFF_T  12288
#define OFF_XF 16384
#define OFF_QS 0
#define OFF_KS 7680
#define OFF_VS 15360
#define OFF_OF 23040
#define OFF_WO 31232
#define LDS_F16 35328

// 4 N-tiles of D = A(16x64) * W(64x64) via 16x16x32 f16 MFMA (2 k-steps each).
// wmat in B-frag order: vec-index = ntile*128 + kstep*64 + lane.
__device__ __forceinline__ void mm4(f16x8 a0, f16x8 a1, const _Float16* wmat,
                                    int lane, f32x4* acc) {
    const f16x8* wv = (const f16x8*)wmat;
    #pragma unroll
    for (int nt = 0; nt < 4; ++nt) {
        f32x4 z = {0.f, 0.f, 0.f, 0.f};
        z = __builtin_amdgcn_mfma_f32_16x16x32_f16(a0, wv[nt * 128 + lane], z, 0, 0, 0);
        z = __builtin_amdgcn_mfma_f32_16x16x32_f16(a1, wv[nt * 128 + 64 + lane], z, 0, 0, 0);
        acc[nt] = z;
    }
}

// A-frag f16 index for A[row][d]:
// (row>>4)*1024 + (d>>5)*512 + ((d>>3)&3)*128 + (row&15)*8 + (d&7)
__global__ __launch_bounds__(512, 4) void fused_kdn(
    const float* __restrict__ x, const float* __restrict__ g_norm,
    const float* __restrict__ Wq, const float* __restrict__ Wk,
    const float* __restrict__ Wv, const float* __restrict__ bv,
    const float* __restrict__ Wo, const float* __restrict__ bo,
    const float* __restrict__ g_post,
    const float* __restrict__ W1, const float* __restrict__ b1,
    const float* __restrict__ W2, const float* __restrict__ b2,
    float* out)
{
    __shared__ __align__(16) _Float16 L[LDS_F16];
    __shared__ float g_s[N_];          // gamma stays fp32 (decay bias compounds ^120)
    __shared__ float bv_s[64], bo_s[64];
    __shared__ float sW1[128], sb1[16], sW2[16], sb2_s[1];

    int tid = threadIdx.x, wave = tid >> 6, lane = tid & 63;
    int b = blockIdx.x;

    // ---------------- setup ----------------
    if (tid < 128) sW1[tid] = W1[tid];
    if (tid >= 128 && tid < 144) sb1[tid - 128] = b1[tid - 128];
    if (tid >= 144 && tid < 160) sW2[tid - 144] = W2[tid - 144];
    if (tid == 160) sb2_s[0] = b2[0];
    if (tid >= 192 && tid < 256) bv_s[tid - 192] = bv[tid - 192];
    if (tid >= 256 && tid < 320) bo_s[tid - 256] = bo[tid - 256];
    if (tid < 128) {   // zero A-frag tile 7 (pad rows 120..127) for xf and o_f
        f16x8 z = {0, 0, 0, 0, 0, 0, 0, 0};
        *(f16x8*)&L[OFF_XF + 7168 + tid * 8] = z;
        *(f16x8*)&L[OFF_OF + 7168 + tid * 8] = z;
    }
    int sn = tid & 63, sk0 = (tid >> 6) * 8;
    int widx = (sn >> 4) * 1024 + (sk0 >> 5) * 512 + ((((sk0 >> 3) & 3) << 4) + (sn & 15)) * 8;
    {
        const float* Ws[4] = { Wq, Wk, Wv, Wo };
        const int woff[4] = { OFF_WQ, OFF_WK, OFF_WV, OFF_WO };
        #pragma unroll
        for (int m = 0; m < 4; ++m) {
            f16x8 pv;
            #pragma unroll
            for (int j = 0; j < 8; ++j) pv[j] = (_Float16)Ws[m][(sk0 + j) * 64 + sn];
            *(f16x8*)&L[woff[m] + widx] = pv;
        }
        // DFT table: T[k][n] = n<32 ? cos(2pi k n/64) : sin(2pi k (n-32)/64)
        f16x8 pv;
        int nn = sn & 31;
        #pragma unroll
        for (int j = 0; j < 8; ++j) {
            int kk = ((sk0 + j) * nn) & 63;
            float a = (float)kk * (6.283185307179586f / 64.0f);
            float s, c; __sincosf(a, &s, &c);
            pv[j] = (_Float16)((sn < 32) ? c : s);
        }
        *(f16x8*)&L[OFF_T + widx] = pv;
    }
    __syncthreads();

    const float* xb = x + (size_t)b * N_ * 64;
    float* ob_g = out + (size_t)b * N_ * 64;

    // ---------------- stage 1: zc_rms(x) -> xf (A-frag fp16) ----------------
    {
        float gn = g_norm[lane];
        int hbase = (lane >> 5) * 512 + ((lane >> 3) & 3) * 128 + (lane & 7);
        #pragma unroll 5
        for (int c = 0; c < 15; ++c) {
            int row = wave * 15 + c;
            float xv = xb[row * 64 + lane];
            float sx = xv, sxx = xv * xv;
            #pragma unroll
            for (int m = 1; m < 64; m <<= 1) { sx += __shfl_xor(sx, m); sxx += __shfl_xor(sxx, m); }
            float mean = sx * 0.015625f;
            float var  = sxx * 0.015625f - mean * mean;
            float h = (xv - mean) * rsqrtf(var + 1e-8f) * gn;
            float hp = __shfl_xor(h, 1);
            if (!(lane & 1)) {
                f16x2 pk2 = { (_Float16)h, (_Float16)hp };
                *(f16x2*)&L[OFF_XF + (row >> 4) * 1024 + (row & 15) * 8 + hbase] = pk2;
            }
        }
    }
    __syncthreads();

    // ---------------- stage 2: MFMA projections ----------------
    int grp = lane >> 4, li = lane & 15;
    int rbase = wave * 16 + grp * 4;
    {
        const f16x8* hfv = (const f16x8*)(L + OFF_XF);
        f16x8 a0 = hfv[wave * 128 + lane];
        f16x8 a1 = hfv[wave * 128 + 64 + lane];
        f32x4 accT[4];

        // gamma: |rfft| bins 0..31 (re: nt 0,1; im: nt 2,3), bands, MLP
        mm4(a0, a1, L + OFF_T, lane, accT);
        {
            int gb2 = lane & 48;
            #pragma unroll
            for (int reg = 0; reg < 4; ++reg) {
                float re1 = accT[0][reg], re2 = accT[1][reg];
                float im1 = accT[2][reg], im2 = accT[3][reg];
                float m1 = sqrtf(fmaf(re1, re1, im1 * im1));
                float m2 = sqrtf(fmaf(re2, re2, im2 * im2));
                m1 += __shfl_xor(m1, 1); m2 += __shfl_xor(m2, 1);
                m1 += __shfl_xor(m1, 2); m2 += __shfl_xor(m2, 2);
                float e1 = m1 * 0.25f, e2 = m2 * 0.25f;       // bands li>>2, 4+(li>>2)
                float tot = e1 + e2;
                tot += __shfl_xor(tot, 4); tot += __shfl_xor(tot, 8);
                float rinv = 1.0f / fmaxf(tot, 1e-8f);
                float en1 = e1 * rinv, en2 = e2 * rinv;
                float hs = sb1[li];
                #pragma unroll
                for (int i = 0; i < 4; ++i)
                    hs = fmaf(__shfl(en1, gb2 + (i << 2)), sW1[i * 16 + li], hs);
                #pragma unroll
                for (int i = 0; i < 4; ++i)
                    hs = fmaf(__shfl(en2, gb2 + (i << 2)), sW1[(i + 4) * 16 + li], hs);
                float act = hs / (1.0f + __expf(-hs));        // silu
                float p = act * sW2[li];
                p += __shfl_xor(p, 1); p += __shfl_xor(p, 2);
                p += __shfl_xor(p, 4); p += __shfl_xor(p, 8);
                float raw = 1.0f / (1.0f + __expf(-(p + sb2_s[0])));
                int row = rbase + reg;
                if (li == 0 && row < N_) g_s[row] = fmaf(0.49f, raw, 0.5f);
            }
        }

        f32x4 accq[4], acck[4], accv[4];
        mm4(a0, a1, L + OFF_WQ, lane, accq);
        mm4(a0, a1, L + OFF_WK, lane, acck);
        mm4(a0, a1, L + OFF_WV, lane, accv);

        {
            f32x4 sq = accq[0]*accq[0] + accq[1]*accq[1] + accq[2]*accq[2] + accq[3]*accq[3];
            f32x4 sk = acck[0]*acck[0] + acck[1]*acck[1] + acck[2]*acck[2] + acck[3]*acck[3];
            #pragma unroll
            for (int reg = 0; reg < 4; ++reg) {
                float qs = sq[reg], ks = sk[reg];
                #pragma unroll
                for (int m = 1; m < 16; m <<= 1) { qs += __shfl_xor(qs, m); ks += __shfl_xor(ks, m); }
                float rq = rsqrtf(qs + 1e-8f), rk = rsqrtf(ks + 1e-8f);
                #pragma unroll
                for (int nt = 0; nt < 4; ++nt) { accq[nt][reg] *= rq; acck[nt][reg] *= rk; }
            }
            #pragma unroll
            for (int nt = 0; nt < 4; ++nt) {
                float bvn = bv_s[nt * 16 + li];
                #pragma unroll
                for (int reg = 0; reg < 4; ++reg) accv[nt][reg] += bvn;
            }
        }
        __syncthreads();   // all waves done reading Wq/Wk/Wv/T/xf

        // writeback q/k/v as fp16, NATURAL column layout (R5-proven)
        #pragma unroll
        for (int reg = 0; reg < 4; ++reg) {
            int row = rbase + reg;
            if (row < N_) {
                int base = row * 64 + li;
                #pragma unroll
                for (int nt = 0; nt < 4; ++nt) {
                    L[OFF_QS + base + nt * 16] = (_Float16)accq[nt][reg];
                    L[OFF_KS + base + nt * 16] = (_Float16)acck[nt][reg];
                    L[OFF_VS + base + nt * 16] = (_Float16)accv[nt][reg];
                }
            }
        }
    }
    __syncthreads();

    // ---------------- stage 3: scan — fp32 S/gamma, f16 k/q/v ----------------
    // Lane-role swap vs R5: col-group in LOW lane bits so both reductions are
    // shfl_xor(1/2/4) (within 32 lanes, single ds_swizzle) instead of 8/16/32.
    {
        int g8 = lane & 7, dlo = lane >> 3;
        int d = wave * 8 + dlo;
        int co = g8 * 8;
        int dbase = (d >> 5) * 512 + ((d >> 3) & 3) * 128 + (d & 7);
        const _Float16* ks = L + OFF_KS;
        const _Float16* qs = L + OFF_QS;
        const _Float16* vs = L + OFF_VS;

        float S[8];
        #pragma unroll
        for (int j = 0; j < 8; ++j) S[j] = 0.f;

        f16x8 kh = *(const f16x8*)&ks[co];
        f16x8 qh = *(const f16x8*)&qs[co];
        _Float16 vh = vs[d];
        float gt = g_s[0];

        for (int t = 0; t < N_; ++t) {
            int tn = (t + 1 < N_) ? (t + 1) : t;
            f16x8 khn = *(const f16x8*)&ks[tn * 64 + co];
            f16x8 qhn = *(const f16x8*)&qs[tn * 64 + co];
            _Float16 vhn = vs[tn * 64 + d];
            float gtn = g_s[tn];

            float p0 = 0.f, p1 = 0.f, p2 = 0.f, p3 = 0.f;
            p0 = fmaf(S[0], (float)kh[0], p0); p1 = fmaf(S[1], (float)kh[1], p1);
            p2 = fmaf(S[2], (float)kh[2], p2); p3 = fmaf(S[3], (float)kh[3], p3);
            p0 = fmaf(S[4], (float)kh[4], p0); p1 = fmaf(S[5], (float)kh[5], p1);
            p2 = fmaf(S[6], (float)kh[6], p2); p3 = fmaf(S[7], (float)kh[7], p3);
            float p = (p0 + p1) + (p2 + p3);
            p += __shfl_xor(p, 1); p += __shfl_xor(p, 2); p += __shfl_xor(p, 4);

            float delta = __builtin_amdgcn_fmed3f((float)vh - p, -5.0f, 5.0f);

            float oa = 0.f, ob = 0.f;
#define UPD(j, oo) { float s = fmaf(delta, (float)kh[j], gt * S[j]);           \
                     s = __builtin_amdgcn_fmed3f(s, -10.f, 10.f); S[j] = s;    \
                     oo = fmaf(s, (float)qh[j], oo); }
            UPD(0, oa) UPD(1, ob) UPD(2, oa) UPD(3, ob)
            UPD(4, oa) UPD(5, ob) UPD(6, oa) UPD(7, ob)
#undef UPD
            float o = oa + ob;
            o += __shfl_xor(o, 1); o += __shfl_xor(o, 2); o += __shfl_xor(o, 4);
            if (g8 == 0)
                L[OFF_OF + (t >> 4) * 1024 + (t & 15) * 8 + dbase] = (_Float16)o;

            kh = khn; qh = qhn; vh = vhn; gt = gtn;
        }
    }
    __syncthreads();

    // ---------------- stage 4a: zc_rms(o) in place in o_f (A-frag) ----------------
    {
        float gp = g_post[lane];
        int hbase = (lane >> 5) * 512 + ((lane >> 3) & 3) * 128 + (lane & 7);
        #pragma unroll 5
        for (int c = 0; c < 15; ++c) {
            int row = wave * 15 + c;
            int ridx = OFF_OF + (row >> 4) * 1024 + (row & 15) * 8;
            float ov = (float)L[ridx + hbase];
            float sx = ov, sxx = ov * ov;
            #pragma unroll
            for (int m = 1; m < 64; m <<= 1) { sx += __shfl_xor(sx, m); sxx += __shfl_xor(sxx, m); }
            float mean = sx * 0.015625f;
            float var  = sxx * 0.015625f - mean * mean;
            float hn = (ov - mean) * rsqrtf(var + 1e-8f) * gp;
            float hp = __shfl_xor(hn, 1);
            if (!(lane & 1)) {
                f16x2 pk2 = { (_Float16)hn, (_Float16)hp };
                *(f16x2*)&L[ridx + hbase] = pk2;   // same-wave in-place, DS in-order
            }
        }
    }
    __syncthreads();

    // ---------------- stage 4b: out = x + zc_rms(o) @ Wo + bo ----------------
    {
        const f16x8* hfv = (const f16x8*)(L + OFF_OF);
        f16x8 a0 = hfv[wave * 128 + lane];
        f16x8 a1 = hfv[wave * 128 + 64 + lane];
        f32x4 acc[4];
        mm4(a0, a1, L + OFF_WO, lane, acc);
        #pragma unroll
        for (int reg = 0; reg < 4; ++reg) {
            int row = rbase + reg;
            if (row < N_) {
                #pragma unroll
                for (int nt = 0; nt < 4; ++nt) {
                    int idx = row * 64 + nt * 16 + li;
                    ob_g[idx] = acc[nt][reg] + bo_s[nt * 16 + li] + xb[idx];
                }
            }
        }
    }
}

extern "C" void kernel_launch(void* const* d_in, const int* in_sizes, int n_in,
                              void* d_out, int out_size, void* d_ws, size_t ws_size,
                              hipStream_t stream)
{
    const float* x      = (const float*)d_in[0];
    const float* g_norm = (const float*)d_in[1];
    const float* Wq     = (const float*)d_in[2];
    const float* Wk     = (const float*)d_in[3];
    const float* Wv     = (const float*)d_in[4];
    const float* bv     = (const float*)d_in[5];
    const float* Wo     = (const float*)d_in[6];
    const float* bo     = (const float*)d_in[7];
    const float* g_post = (const float*)d_in[8];
    const float* W1     = (const float*)d_in[9];
    const float* b1     = (const float*)d_in[10];
    const float* W2     = (const float*)d_in[11];
    const float* b2     = (const float*)d_in[12];
    float* out = (float*)d_out;

    fused_kdn<<<B_, 512, 0, stream>>>(x, g_norm, Wq, Wk, Wv, bv, Wo, bo, g_post,
                                      W1, b1, W2, b2, out);
}

// Round 9
// 177.672 us; speedup vs baseline: 1.0115x; 1.0115x over previous
//
#include <hip/hip_runtime.h>
#include <math.h>

#define B_ 512
#define N_ 120

typedef __attribute__((ext_vector_type(8))) _Float16 f16x8;
typedef __attribute__((ext_vector_type(2))) _Float16 f16x2;
typedef __attribute__((ext_vector_type(4))) float f32x4;

union PK { f16x2 h; int i; };

// LDS union buffer offsets (f16 units):
//  phase A (setup..stage2): Wq 0 | Wk 4096 | Wv 8192 | T 12288 | xf 16384..24576
//  phase B (scan):          q_s 0 | k_s 7680 | v_s 15360 | o_f 23040..31232
//  persistent:              Wo 31232..35328
#define OFF_WQ 0
#define OFF_WK 4096
#define OFF_WV 8192
#define OFF_T  12288
#define OFF_XF 16384
#define OFF_QS 0
#define OFF_KS 7680
#define OFF_VS 15360
#define OFF_OF 23040
#define OFF_WO 31232
#define LDS_F16 35328

// 4 N-tiles of D = A(16x64) * W(64x64) via 16x16x32 f16 MFMA (2 k-steps each).
// wmat in B-frag order: vec-index = ntile*128 + kstep*64 + lane.
__device__ __forceinline__ void mm4(f16x8 a0, f16x8 a1, const _Float16* wmat,
                                    int lane, f32x4* acc) {
    const f16x8* wv = (const f16x8*)wmat;
    #pragma unroll
    for (int nt = 0; nt < 4; ++nt) {
        f32x4 z = {0.f, 0.f, 0.f, 0.f};
        z = __builtin_amdgcn_mfma_f32_16x16x32_f16(a0, wv[nt * 128 + lane], z, 0, 0, 0);
        z = __builtin_amdgcn_mfma_f32_16x16x32_f16(a1, wv[nt * 128 + 64 + lane], z, 0, 0, 0);
        acc[nt] = z;
    }
}

// A-frag f16 index for A[row][d]:
// (row>>4)*1024 + (d>>5)*512 + ((d>>3)&3)*128 + (row&15)*8 + (d&7)
__global__ __launch_bounds__(512, 4) void fused_kdn(
    const float* __restrict__ x, const float* __restrict__ g_norm,
    const float* __restrict__ Wq, const float* __restrict__ Wk,
    const float* __restrict__ Wv, const float* __restrict__ bv,
    const float* __restrict__ Wo, const float* __restrict__ bo,
    const float* __restrict__ g_post,
    const float* __restrict__ W1, const float* __restrict__ b1,
    const float* __restrict__ W2, const float* __restrict__ b2,
    float* out)
{
    __shared__ __align__(16) _Float16 L[LDS_F16];
    __shared__ __align__(16) float g_s[N_];  // gamma stays fp32 (decay bias compounds ^120)
    __shared__ float bv_s[64], bo_s[64];
    __shared__ float sW1[128], sb1[16], sW2[16], sb2_s[1];

    int tid = threadIdx.x, wave = tid >> 6, lane = tid & 63;
    int b = blockIdx.x;

    // ---------------- setup ----------------
    if (tid < 128) sW1[tid] = W1[tid];
    if (tid >= 128 && tid < 144) sb1[tid - 128] = b1[tid - 128];
    if (tid >= 144 && tid < 160) sW2[tid - 144] = W2[tid - 144];
    if (tid == 160) sb2_s[0] = b2[0];
    if (tid >= 192 && tid < 256) bv_s[tid - 192] = bv[tid - 192];
    if (tid >= 256 && tid < 320) bo_s[tid - 256] = bo[tid - 256];
    if (tid < 128) {   // zero A-frag tile 7 (pad rows 120..127) for xf and o_f
        f16x8 z = {0, 0, 0, 0, 0, 0, 0, 0};
        *(f16x8*)&L[OFF_XF + 7168 + tid * 8] = z;
        *(f16x8*)&L[OFF_OF + 7168 + tid * 8] = z;
    }
    int sn = tid & 63, sk0 = (tid >> 6) * 8;
    int widx = (sn >> 4) * 1024 + (sk0 >> 5) * 512 + ((((sk0 >> 3) & 3) << 4) + (sn & 15)) * 8;
    {
        const float* Ws[4] = { Wq, Wk, Wv, Wo };
        const int woff[4] = { OFF_WQ, OFF_WK, OFF_WV, OFF_WO };
        #pragma unroll
        for (int m = 0; m < 4; ++m) {
            f16x8 pv;
            #pragma unroll
            for (int j = 0; j < 8; ++j) pv[j] = (_Float16)Ws[m][(sk0 + j) * 64 + sn];
            *(f16x8*)&L[woff[m] + widx] = pv;
        }
        // DFT table: T[k][n] = n<32 ? cos(2pi k n/64) : sin(2pi k (n-32)/64)
        f16x8 pv;
        int nn = sn & 31;
        #pragma unroll
        for (int j = 0; j < 8; ++j) {
            int kk = ((sk0 + j) * nn) & 63;
            float a = (float)kk * (6.283185307179586f / 64.0f);
            float s, c; __sincosf(a, &s, &c);
            pv[j] = (_Float16)((sn < 32) ? c : s);
        }
        *(f16x8*)&L[OFF_T + widx] = pv;
    }
    __syncthreads();

    const float* xb = x + (size_t)b * N_ * 64;
    float* ob_g = out + (size_t)b * N_ * 64;

    // ---------------- stage 1: zc_rms(x) -> xf (A-frag fp16) ----------------
    {
        float gn = g_norm[lane];
        int hbase = (lane >> 5) * 512 + ((lane >> 3) & 3) * 128 + (lane & 7);
        #pragma unroll 5
        for (int c = 0; c < 15; ++c) {
            int row = wave * 15 + c;
            float xv = xb[row * 64 + lane];
            float sx = xv, sxx = xv * xv;
            #pragma unroll
            for (int m = 1; m < 64; m <<= 1) { sx += __shfl_xor(sx, m); sxx += __shfl_xor(sxx, m); }
            float mean = sx * 0.015625f;
            float var  = sxx * 0.015625f - mean * mean;
            float h = (xv - mean) * rsqrtf(var + 1e-8f) * gn;
            float hp = __shfl_xor(h, 1);
            if (!(lane & 1)) {
                f16x2 pk2 = { (_Float16)h, (_Float16)hp };
                *(f16x2*)&L[OFF_XF + (row >> 4) * 1024 + (row & 15) * 8 + hbase] = pk2;
            }
        }
    }
    __syncthreads();

    // ---------------- stage 2: MFMA projections ----------------
    int grp = lane >> 4, li = lane & 15;
    int rbase = wave * 16 + grp * 4;
    {
        const f16x8* hfv = (const f16x8*)(L + OFF_XF);
        f16x8 a0 = hfv[wave * 128 + lane];
        f16x8 a1 = hfv[wave * 128 + 64 + lane];
        f32x4 accT[4];

        // gamma: |rfft| bins 0..31 (re: nt 0,1; im: nt 2,3), bands, MLP
        mm4(a0, a1, L + OFF_T, lane, accT);
        {
            int gb2 = lane & 48;
            #pragma unroll
            for (int reg = 0; reg < 4; ++reg) {
                float re1 = accT[0][reg], re2 = accT[1][reg];
                float im1 = accT[2][reg], im2 = accT[3][reg];
                float m1 = sqrtf(fmaf(re1, re1, im1 * im1));
                float m2 = sqrtf(fmaf(re2, re2, im2 * im2));
                m1 += __shfl_xor(m1, 1); m2 += __shfl_xor(m2, 1);
                m1 += __shfl_xor(m1, 2); m2 += __shfl_xor(m2, 2);
                float e1 = m1 * 0.25f, e2 = m2 * 0.25f;       // bands li>>2, 4+(li>>2)
                float tot = e1 + e2;
                tot += __shfl_xor(tot, 4); tot += __shfl_xor(tot, 8);
                float rinv = 1.0f / fmaxf(tot, 1e-8f);
                float en1 = e1 * rinv, en2 = e2 * rinv;
                float hs = sb1[li];
                #pragma unroll
                for (int i = 0; i < 4; ++i)
                    hs = fmaf(__shfl(en1, gb2 + (i << 2)), sW1[i * 16 + li], hs);
                #pragma unroll
                for (int i = 0; i < 4; ++i)
                    hs = fmaf(__shfl(en2, gb2 + (i << 2)), sW1[(i + 4) * 16 + li], hs);
                float act = hs / (1.0f + __expf(-hs));        // silu
                float p = act * sW2[li];
                p += __shfl_xor(p, 1); p += __shfl_xor(p, 2);
                p += __shfl_xor(p, 4); p += __shfl_xor(p, 8);
                float raw = 1.0f / (1.0f + __expf(-(p + sb2_s[0])));
                int row = rbase + reg;
                if (li == 0 && row < N_) g_s[row] = fmaf(0.49f, raw, 0.5f);
            }
        }

        f32x4 accq[4], acck[4], accv[4];
        mm4(a0, a1, L + OFF_WQ, lane, accq);
        mm4(a0, a1, L + OFF_WK, lane, acck);
        mm4(a0, a1, L + OFF_WV, lane, accv);

        {
            f32x4 sq = accq[0]*accq[0] + accq[1]*accq[1] + accq[2]*accq[2] + accq[3]*accq[3];
            f32x4 sk = acck[0]*acck[0] + acck[1]*acck[1] + acck[2]*acck[2] + acck[3]*acck[3];
            #pragma unroll
            for (int reg = 0; reg < 4; ++reg) {
                float qs = sq[reg], ks = sk[reg];
                #pragma unroll
                for (int m = 1; m < 16; m <<= 1) { qs += __shfl_xor(qs, m); ks += __shfl_xor(ks, m); }
                float rq = rsqrtf(qs + 1e-8f), rk = rsqrtf(ks + 1e-8f);
                #pragma unroll
                for (int nt = 0; nt < 4; ++nt) { accq[nt][reg] *= rq; acck[nt][reg] *= rk; }
            }
            #pragma unroll
            for (int nt = 0; nt < 4; ++nt) {
                float bvn = bv_s[nt * 16 + li];
                #pragma unroll
                for (int reg = 0; reg < 4; ++reg) accv[nt][reg] += bvn;
            }
        }
        __syncthreads();   // all waves done reading Wq/Wk/Wv/T/xf

        // writeback q/k/v as fp16, NATURAL column layout (R5-proven)
        #pragma unroll
        for (int reg = 0; reg < 4; ++reg) {
            int row = rbase + reg;
            if (row < N_) {
                int base = row * 64 + li;
                #pragma unroll
                for (int nt = 0; nt < 4; ++nt) {
                    L[OFF_QS + base + nt * 16] = (_Float16)accq[nt][reg];
                    L[OFF_KS + base + nt * 16] = (_Float16)acck[nt][reg];
                    L[OFF_VS + base + nt * 16] = (_Float16)accv[nt][reg];
                }
            }
        }
    }
    __syncthreads();

    // ---------------- stage 3: scan — fp32 S/gamma, f16 k/q/v ----------------
    // DS-op diet vs R8 (the LDS pipe is the limiter, not VALU):
    //  * software-pipelined p: p(t+1) partials computed right after update(t)
    //    using prefetched k(t+1); packed with o(t) partials as f16x2 and
    //    reduced with ONE 3-hop shfl chain (v_pk_add_f16)  -> 6 shfl/step -> 3
    //  * gamma preloaded 4-at-a-time (b128)                -> 1 b32/step -> 0.25
    //  p(0) = 0 since S0 = 0 (no prologue reduction needed).
    {
        int g8 = lane & 7, dlo = lane >> 3;
        int d = wave * 8 + dlo;
        int co = g8 * 8;
        int dbase = (d >> 5) * 512 + ((d >> 3) & 3) * 128 + (d & 7);
        const _Float16* ks = L + OFF_KS;
        const _Float16* qs = L + OFF_QS;
        const _Float16* vs = L + OFF_VS;

        float S[8];
        #pragma unroll
        for (int j = 0; j < 8; ++j) S[j] = 0.f;

        f16x8 kh = *(const f16x8*)&ks[co];
        f16x8 qh = *(const f16x8*)&qs[co];
        _Float16 vh = vs[d];
        float pbc = 0.f;                          // broadcast pred(0) = 0
        float4 gq = *(const float4*)&g_s[0];

        for (int t4 = 0; t4 < N_; t4 += 4) {
            float4 gq_n = (t4 + 4 < N_) ? *(const float4*)&g_s[t4 + 4] : gq;
            #pragma unroll
            for (int j4 = 0; j4 < 4; ++j4) {
                int t = t4 + j4;
                int tn = (t + 1 < N_) ? (t + 1) : t;
                f16x8 khn = *(const f16x8*)&ks[tn * 64 + co];
                f16x8 qhn = *(const f16x8*)&qs[tn * 64 + co];
                _Float16 vhn = vs[tn * 64 + d];
                float gt = (j4 == 0) ? gq.x : (j4 == 1) ? gq.y : (j4 == 2) ? gq.z : gq.w;

                float delta = __builtin_amdgcn_fmed3f((float)vh - pbc, -5.0f, 5.0f);

                float oa = 0.f, ob = 0.f, pa = 0.f, pb = 0.f;
#define UPD(j, oo, pp) { float s = fmaf(delta, (float)kh[j], gt * S[j]);       \
                     s = __builtin_amdgcn_fmed3f(s, -10.f, 10.f); S[j] = s;    \
                     oo = fmaf(s, (float)qh[j], oo);                           \
                     pp = fmaf(s, (float)khn[j], pp); }
                UPD(0, oa, pa) UPD(1, ob, pb) UPD(2, oa, pa) UPD(3, ob, pb)
                UPD(4, oa, pa) UPD(5, ob, pb) UPD(6, oa, pa) UPD(7, ob, pb)
#undef UPD
                PK pk;
                pk.h[0] = (_Float16)(oa + ob);    // o(t) partial
                pk.h[1] = (_Float16)(pa + pb);    // p(t+1) partial
                PK r1; r1.i = __shfl_xor(pk.i, 1); pk.h = pk.h + r1.h;
                PK r2; r2.i = __shfl_xor(pk.i, 2); pk.h = pk.h + r2.h;
                PK r4; r4.i = __shfl_xor(pk.i, 4); pk.h = pk.h + r4.h;

                if (g8 == 0)
                    L[OFF_OF + (t >> 4) * 1024 + (t & 15) * 8 + dbase] = pk.h[0];
                pbc = (float)pk.h[1];

                kh = khn; qh = qhn; vh = vhn;
            }
            gq = gq_n;
        }
    }
    __syncthreads();

    // ---------------- stage 4a: zc_rms(o) in place in o_f (A-frag) ----------------
    {
        float gp = g_post[lane];
        int hbase = (lane >> 5) * 512 + ((lane >> 3) & 3) * 128 + (lane & 7);
        #pragma unroll 5
        for (int c = 0; c < 15; ++c) {
            int row = wave * 15 + c;
            int ridx = OFF_OF + (row >> 4) * 1024 + (row & 15) * 8;
            float ov = (float)L[ridx + hbase];
            float sx = ov, sxx = ov * ov;
            #pragma unroll
            for (int m = 1; m < 64; m <<= 1) { sx += __shfl_xor(sx, m); sxx += __shfl_xor(sxx, m); }
            float mean = sx * 0.015625f;
            float var  = sxx * 0.015625f - mean * mean;
            float hn = (ov - mean) * rsqrtf(var + 1e-8f) * gp;
            float hp = __shfl_xor(hn, 1);
            if (!(lane & 1)) {
                f16x2 pk2 = { (_Float16)hn, (_Float16)hp };
                *(f16x2*)&L[ridx + hbase] = pk2;   // same-wave in-place, DS in-order
            }
        }
    }
    __syncthreads();

    // ---------------- stage 4b: out = x + zc_rms(o) @ Wo + bo ----------------
    {
        const f16x8* hfv = (const f16x8*)(L + OFF_OF);
        f16x8 a0 = hfv[wave * 128 + lane];
        f16x8 a1 = hfv[wave * 128 + 64 + lane];
        f32x4 acc[4];
        mm4(a0, a1, L + OFF_WO, lane, acc);
        #pragma unroll
        for (int reg = 0; reg < 4; ++reg) {
            int row = rbase + reg;
            if (row < N_) {
                #pragma unroll
                for (int nt = 0; nt < 4; ++nt) {
                    int idx = row * 64 + nt * 16 + li;
                    ob_g[idx] = acc[nt][reg] + bo_s[nt * 16 + li] + xb[idx];
                }
            }
        }
    }
}

extern "C" void kernel_launch(void* const* d_in, const int* in_sizes, int n_in,
                              void* d_out, int out_size, void* d_ws, size_t ws_size,
                              hipStream_t stream)
{
    const float* x      = (const float*)d_in[0];
    const float* g_norm = (const float*)d_in[1];
    const float* Wq     = (const float*)d_in[2];
    const float* Wk     = (const float*)d_in[3];
    const float* Wv     = (const float*)d_in[4];
    const float* bv     = (const float*)d_in[5];
    const float* Wo     = (const float*)d_in[6];
    const float* bo     = (const float*)d_in[7];
    const float* g_post = (const float*)d_in[8];
    const float* W1     = (const float*)d_in[9];
    const float* b1     = (const float*)d_in[10];
    const float* W2     = (const float*)d_in[11];
    const float* b2     = (const float*)d_in[12];
    float* out = (float*)d_out;

    fused_kdn<<<B_, 512, 0, stream>>>(x, g_norm, Wq, Wk, Wv, bv, Wo, bo, g_post,
                                      W1, b1, W2, b2, out);
}

// Round 11
// 163.973 us; speedup vs baseline: 1.0960x; 1.0835x over previous
//
#include <hip/hip_runtime.h>
#include <math.h>

#define B_ 512
#define N_ 120

typedef __attribute__((ext_vector_type(8))) _Float16 f16x8;
typedef __attribute__((ext_vector_type(2))) _Float16 f16x2;
typedef __attribute__((ext_vector_type(4))) float f32x4;

// DPP cross-lane add on the VALU pipe (no DS op). Trees are bitwise identical
// to shfl_xor butterflies: 0xB1=xor1, 0x4E=xor2; 0x141 (row_half_mirror) and
// 0x140 (row_mirror) are valid xor4/xor8 substitutes ONLY after the previous
// hops have made quads/8-halves uniform (fp add commutativity => bitwise same).
#define DPP_XOR1 0xB1
#define DPP_XOR2 0x4E
#define DPP_HMIR 0x141
#define DPP_MIR  0x140
template<int CTRL>
__device__ __forceinline__ float dpp_add(float v) {
    int x = __builtin_amdgcn_mov_dpp(__float_as_int(v), CTRL, 0xF, 0xF, true);
    return v + __int_as_float(x);
}

// LDS union buffer offsets (f16 units):
//  phase A (setup..stage2): Wq 0 | Wk 4096 | Wv 8192 | T 12288 | xf 16384..24576
//  phase B (scan):          q_s 0 | k_s 7680 | v_s 15360 | o_f 23040..31232
//  persistent:              Wo 31232..35328
#define OFF_WQ 0
#define OFF_WK 4096
#define OFF_WV 8192
#define OFF_T  12288
#define OFF_XF 16384
#define OFF_QS 0
#define OFF_KS 7680
#define OFF_VS 15360
#define OFF_OF 23040
#define OFF_WO 31232
#define LDS_F16 35328

// 4 N-tiles of D = A(16x64) * W(64x64) via 16x16x32 f16 MFMA (2 k-steps each).
// wmat in B-frag order: vec-index = ntile*128 + kstep*64 + lane.
__device__ __forceinline__ void mm4(f16x8 a0, f16x8 a1, const _Float16* wmat,
                                    int lane, f32x4* acc) {
    const f16x8* wv = (const f16x8*)wmat;
    #pragma unroll
    for (int nt = 0; nt < 4; ++nt) {
        f32x4 z = {0.f, 0.f, 0.f, 0.f};
        z = __builtin_amdgcn_mfma_f32_16x16x32_f16(a0, wv[nt * 128 + lane], z, 0, 0, 0);
        z = __builtin_amdgcn_mfma_f32_16x16x32_f16(a1, wv[nt * 128 + 64 + lane], z, 0, 0, 0);
        acc[nt] = z;
    }
}

// A-frag f16 index for A[row][d]:
// (row>>4)*1024 + (d>>5)*512 + ((d>>3)&3)*128 + (row&15)*8 + (d&7)
__global__ __launch_bounds__(512, 4) void fused_kdn(
    const float* __restrict__ x, const float* __restrict__ g_norm,
    const float* __restrict__ Wq, const float* __restrict__ Wk,
    const float* __restrict__ Wv, const float* __restrict__ bv,
    const float* __restrict__ Wo, const float* __restrict__ bo,
    const float* __restrict__ g_post,
    const float* __restrict__ W1, const float* __restrict__ b1,
    const float* __restrict__ W2, const float* __restrict__ b2,
    float* out)
{
    __shared__ __align__(16) _Float16 L[LDS_F16];
    __shared__ __align__(16) float g_s[N_];  // gamma stays fp32 (decay bias compounds ^120)
    __shared__ float bv_s[64], bo_s[64];
    __shared__ float sW1[128], sb1[16], sW2[16], sb2_s[1];

    int tid = threadIdx.x, wave = tid >> 6, lane = tid & 63;
    int b = blockIdx.x;

    // ---------------- setup ----------------
    if (tid < 128) sW1[tid] = W1[tid];
    if (tid >= 128 && tid < 144) sb1[tid - 128] = b1[tid - 128];
    if (tid >= 144 && tid < 160) sW2[tid - 144] = W2[tid - 144];
    if (tid == 160) sb2_s[0] = b2[0];
    if (tid >= 192 && tid < 256) bv_s[tid - 192] = bv[tid - 192];
    if (tid >= 256 && tid < 320) bo_s[tid - 256] = bo[tid - 256];
    if (tid < 128) {   // zero A-frag tile 7 (pad rows 120..127) for xf and o_f
        f16x8 z = {0, 0, 0, 0, 0, 0, 0, 0};
        *(f16x8*)&L[OFF_XF + 7168 + tid * 8] = z;
        *(f16x8*)&L[OFF_OF + 7168 + tid * 8] = z;
    }
    int sn = tid & 63, sk0 = (tid >> 6) * 8;
    int widx = (sn >> 4) * 1024 + (sk0 >> 5) * 512 + ((((sk0 >> 3) & 3) << 4) + (sn & 15)) * 8;
    {
        const float* Ws[4] = { Wq, Wk, Wv, Wo };
        const int woff[4] = { OFF_WQ, OFF_WK, OFF_WV, OFF_WO };
        #pragma unroll
        for (int m = 0; m < 4; ++m) {
            f16x8 pv;
            #pragma unroll
            for (int j = 0; j < 8; ++j) pv[j] = (_Float16)Ws[m][(sk0 + j) * 64 + sn];
            *(f16x8*)&L[woff[m] + widx] = pv;
        }
        // DFT table: T[k][n] = n<32 ? cos(2pi k n/64) : sin(2pi k (n-32)/64)
        f16x8 pv;
        int nn = sn & 31;
        #pragma unroll
        for (int j = 0; j < 8; ++j) {
            int kk = ((sk0 + j) * nn) & 63;
            float a = (float)kk * (6.283185307179586f / 64.0f);
            float s, c; __sincosf(a, &s, &c);
            pv[j] = (_Float16)((sn < 32) ? c : s);
        }
        *(f16x8*)&L[OFF_T + widx] = pv;
    }
    __syncthreads();

    const float* xb = x + (size_t)b * N_ * 64;
    float* ob_g = out + (size_t)b * N_ * 64;

    // ---------------- stage 1: zc_rms(x) -> xf (A-frag fp16) ----------------
    // R8/R9-proven 15-row structure; reduction hops 1-8 on DPP, 16/32 on shfl.
    {
        float gn = g_norm[lane];
        int hbase = (lane >> 5) * 512 + ((lane >> 3) & 3) * 128 + (lane & 7);
        #pragma unroll 5
        for (int c = 0; c < 15; ++c) {
            int row = wave * 15 + c;
            float xv = xb[row * 64 + lane];
            float sx = xv, sxx = xv * xv;
            sx = dpp_add<DPP_XOR1>(sx); sxx = dpp_add<DPP_XOR1>(sxx);
            sx = dpp_add<DPP_XOR2>(sx); sxx = dpp_add<DPP_XOR2>(sxx);
            sx = dpp_add<DPP_HMIR>(sx); sxx = dpp_add<DPP_HMIR>(sxx);
            sx = dpp_add<DPP_MIR >(sx); sxx = dpp_add<DPP_MIR >(sxx);
            sx += __shfl_xor(sx, 16);   sxx += __shfl_xor(sxx, 16);
            sx += __shfl_xor(sx, 32);   sxx += __shfl_xor(sxx, 32);
            float mean = sx * 0.015625f;
            float var  = sxx * 0.015625f - mean * mean;
            float h = (xv - mean) * rsqrtf(var + 1e-8f) * gn;
            float hp = __shfl_xor(h, 1);
            if (!(lane & 1)) {
                f16x2 pk2 = { (_Float16)h, (_Float16)hp };
                *(f16x2*)&L[OFF_XF + (row >> 4) * 1024 + (row & 15) * 8 + hbase] = pk2;
            }
        }
    }
    __syncthreads();

    // ---------------- stage 2: MFMA projections ----------------
    int grp = lane >> 4, li = lane & 15;
    int rbase = wave * 16 + grp * 4;
    {
        const f16x8* hfv = (const f16x8*)(L + OFF_XF);
        f16x8 a0 = hfv[wave * 128 + lane];
        f16x8 a1 = hfv[wave * 128 + 64 + lane];
        f32x4 accT[4];

        // gamma: |rfft| bins 0..31 (re: nt 0,1; im: nt 2,3), bands, MLP
        mm4(a0, a1, L + OFF_T, lane, accT);
        {
            int gb2 = lane & 48;
            #pragma unroll
            for (int reg = 0; reg < 4; ++reg) {
                float re1 = accT[0][reg], re2 = accT[1][reg];
                float im1 = accT[2][reg], im2 = accT[3][reg];
                float m1 = sqrtf(fmaf(re1, re1, im1 * im1));
                float m2 = sqrtf(fmaf(re2, re2, im2 * im2));
                m1 = dpp_add<DPP_XOR1>(m1); m2 = dpp_add<DPP_XOR1>(m2);
                m1 = dpp_add<DPP_XOR2>(m1); m2 = dpp_add<DPP_XOR2>(m2);
                float e1 = m1 * 0.25f, e2 = m2 * 0.25f;       // bands li>>2, 4+(li>>2)
                float tot = e1 + e2;
                tot = dpp_add<DPP_HMIR>(tot);   // xor4 (quads uniform after m-hops)
                tot = dpp_add<DPP_MIR >(tot);   // xor8
                float rinv = 1.0f / fmaxf(tot, 1e-8f);
                float en1 = e1 * rinv, en2 = e2 * rinv;
                float hs = sb1[li];
                #pragma unroll
                for (int i = 0; i < 4; ++i)
                    hs = fmaf(__shfl(en1, gb2 + (i << 2)), sW1[i * 16 + li], hs);
                #pragma unroll
                for (int i = 0; i < 4; ++i)
                    hs = fmaf(__shfl(en2, gb2 + (i << 2)), sW1[(i + 4) * 16 + li], hs);
                float act = hs / (1.0f + __expf(-hs));        // silu
                float p = act * sW2[li];
                p = dpp_add<DPP_XOR1>(p);
                p = dpp_add<DPP_XOR2>(p);
                p = dpp_add<DPP_HMIR>(p);
                p = dpp_add<DPP_MIR >(p);
                float raw = 1.0f / (1.0f + __expf(-(p + sb2_s[0])));
                int row = rbase + reg;
                if (li == 0 && row < N_) g_s[row] = fmaf(0.49f, raw, 0.5f);
            }
        }

        f32x4 accq[4], acck[4], accv[4];
        mm4(a0, a1, L + OFF_WQ, lane, accq);
        mm4(a0, a1, L + OFF_WK, lane, acck);
        mm4(a0, a1, L + OFF_WV, lane, accv);

        {
            f32x4 sq = accq[0]*accq[0] + accq[1]*accq[1] + accq[2]*accq[2] + accq[3]*accq[3];
            f32x4 sk = acck[0]*acck[0] + acck[1]*acck[1] + acck[2]*acck[2] + acck[3]*acck[3];
            #pragma unroll
            for (int reg = 0; reg < 4; ++reg) {
                float qs = sq[reg], ks = sk[reg];
                qs = dpp_add<DPP_XOR1>(qs); ks = dpp_add<DPP_XOR1>(ks);
                qs = dpp_add<DPP_XOR2>(qs); ks = dpp_add<DPP_XOR2>(ks);
                qs = dpp_add<DPP_HMIR>(qs); ks = dpp_add<DPP_HMIR>(ks);
                qs = dpp_add<DPP_MIR >(qs); ks = dpp_add<DPP_MIR >(ks);
                float rq = rsqrtf(qs + 1e-8f), rk = rsqrtf(ks + 1e-8f);
                #pragma unroll
                for (int nt = 0; nt < 4; ++nt) { accq[nt][reg] *= rq; acck[nt][reg] *= rk; }
            }
            #pragma unroll
            for (int nt = 0; nt < 4; ++nt) {
                float bvn = bv_s[nt * 16 + li];
                #pragma unroll
                for (int reg = 0; reg < 4; ++reg) accv[nt][reg] += bvn;
            }
        }
        __syncthreads();   // all waves done reading Wq/Wk/Wv/T/xf

        // writeback q/k/v as fp16, NATURAL column layout (R5-proven)
        #pragma unroll
        for (int reg = 0; reg < 4; ++reg) {
            int row = rbase + reg;
            if (row < N_) {
                int base = row * 64 + li;
                #pragma unroll
                for (int nt = 0; nt < 4; ++nt) {
                    L[OFF_QS + base + nt * 16] = (_Float16)accq[nt][reg];
                    L[OFF_KS + base + nt * 16] = (_Float16)acck[nt][reg];
                    L[OFF_VS + base + nt * 16] = (_Float16)accv[nt][reg];
                }
            }
        }
    }
    __syncthreads();

    // ---------------- stage 3: scan — fp32 S/gamma/reductions, f16 k/q/v ----
    //  * o and p reduced via 3 DPP-adds each (VALU pipe, fp32, zero DS shuffles)
    //  * software-pipelined p: p(t+1) partials vs prefetched k(t+1)
    //  * gamma preloaded 4-at-a-time (b128);  p(0)=0 since S0=0.
    {
        int g8 = lane & 7, dlo = lane >> 3;
        int d = wave * 8 + dlo;
        int co = g8 * 8;
        int dbase = (d >> 5) * 512 + ((d >> 3) & 3) * 128 + (d & 7);
        const _Float16* ks = L + OFF_KS;
        const _Float16* qs = L + OFF_QS;
        const _Float16* vs = L + OFF_VS;

        float S[8];
        #pragma unroll
        for (int j = 0; j < 8; ++j) S[j] = 0.f;

        f16x8 kh = *(const f16x8*)&ks[co];
        f16x8 qh = *(const f16x8*)&qs[co];
        _Float16 vh = vs[d];
        float pbc = 0.f;                          // broadcast pred(0) = 0
        float4 gq = *(const float4*)&g_s[0];

        for (int t4 = 0; t4 < N_; t4 += 4) {
            float4 gq_n = (t4 + 4 < N_) ? *(const float4*)&g_s[t4 + 4] : gq;
            #pragma unroll
            for (int j4 = 0; j4 < 4; ++j4) {
                int t = t4 + j4;
                int tn = (t + 1 < N_) ? (t + 1) : t;
                f16x8 khn = *(const f16x8*)&ks[tn * 64 + co];
                f16x8 qhn = *(const f16x8*)&qs[tn * 64 + co];
                _Float16 vhn = vs[tn * 64 + d];
                float gt = (j4 == 0) ? gq.x : (j4 == 1) ? gq.y : (j4 == 2) ? gq.z : gq.w;

                float delta = __builtin_amdgcn_fmed3f((float)vh - pbc, -5.0f, 5.0f);

                float oa = 0.f, ob = 0.f, pa = 0.f, pb = 0.f;
#define UPD(j, oo, pp) { float s = fmaf(delta, (float)kh[j], gt * S[j]);       \
                     s = __builtin_amdgcn_fmed3f(s, -10.f, 10.f); S[j] = s;    \
                     oo = fmaf(s, (float)qh[j], oo);                           \
                     pp = fmaf(s, (float)khn[j], pp); }
                UPD(0, oa, pa) UPD(1, ob, pb) UPD(2, oa, pa) UPD(3, ob, pb)
                UPD(4, oa, pa) UPD(5, ob, pb) UPD(6, oa, pa) UPD(7, ob, pb)
#undef UPD
                float o = oa + ob;
                o = dpp_add<DPP_XOR1>(o);
                o = dpp_add<DPP_XOR2>(o);
                o = dpp_add<DPP_HMIR>(o);
                float pn = pa + pb;
                pn = dpp_add<DPP_XOR1>(pn);
                pn = dpp_add<DPP_XOR2>(pn);
                pn = dpp_add<DPP_HMIR>(pn);

                if (g8 == 0)
                    L[OFF_OF + (t >> 4) * 1024 + (t & 15) * 8 + dbase] = (_Float16)o;
                pbc = pn;

                kh = khn; qh = qhn; vh = vhn;
            }
            gq = gq_n;
        }
    }
    __syncthreads();

    // ---------------- stage 4a: zc_rms(o) in place in o_f (A-frag) ----------------
    {
        float gp = g_post[lane];
        int hbase = (lane >> 5) * 512 + ((lane >> 3) & 3) * 128 + (lane & 7);
        #pragma unroll 5
        for (int c = 0; c < 15; ++c) {
            int row = wave * 15 + c;
            int ridx = OFF_OF + (row >> 4) * 1024 + (row & 15) * 8;
            float ov = (float)L[ridx + hbase];
            float sx = ov, sxx = ov * ov;
            sx = dpp_add<DPP_XOR1>(sx); sxx = dpp_add<DPP_XOR1>(sxx);
            sx = dpp_add<DPP_XOR2>(sx); sxx = dpp_add<DPP_XOR2>(sxx);
            sx = dpp_add<DPP_HMIR>(sx); sxx = dpp_add<DPP_HMIR>(sxx);
            sx = dpp_add<DPP_MIR >(sx); sxx = dpp_add<DPP_MIR >(sxx);
            sx += __shfl_xor(sx, 16);   sxx += __shfl_xor(sxx, 16);
            sx += __shfl_xor(sx, 32);   sxx += __shfl_xor(sxx, 32);
            float mean = sx * 0.015625f;
            float var  = sxx * 0.015625f - mean * mean;
            float hn = (ov - mean) * rsqrtf(var + 1e-8f) * gp;
            float hp = __shfl_xor(hn, 1);
            if (!(lane & 1)) {
                f16x2 pk2 = { (_Float16)hn, (_Float16)hp };
                *(f16x2*)&L[ridx + hbase] = pk2;   // same-wave in-place, DS in-order
            }
        }
    }
    __syncthreads();

    // ---------------- stage 4b: out = x + zc_rms(o) @ Wo + bo ----------------
    {
        const f16x8* hfv = (const f16x8*)(L + OFF_OF);
        f16x8 a0 = hfv[wave * 128 + lane];
        f16x8 a1 = hfv[wave * 128 + 64 + lane];
        f32x4 acc[4];
        mm4(a0, a1, L + OFF_WO, lane, acc);
        #pragma unroll
        for (int reg = 0; reg < 4; ++reg) {
            int row = rbase + reg;
            if (row < N_) {
                #pragma unroll
                for (int nt = 0; nt < 4; ++nt) {
                    int idx = row * 64 + nt * 16 + li;
                    ob_g[idx] = acc[nt][reg] + bo_s[nt * 16 + li] + xb[idx];
                }
            }
        }
    }
}

extern "C" void kernel_launch(void* const* d_in, const int* in_sizes, int n_in,
                              void* d_out, int out_size, void* d_ws, size_t ws_size,
                              hipStream_t stream)
{
    const float* x      = (const float*)d_in[0];
    const float* g_norm = (const float*)d_in[1];
    const float* Wq     = (const float*)d_in[2];
    const float* Wk     = (const float*)d_in[3];
    const float* Wv     = (const float*)d_in[4];
    const float* bv     = (const float*)d_in[5];
    const float* Wo     = (const float*)d_in[6];
    const float* bo     = (const float*)d_in[7];
    const float* g_post = (const float*)d_in[8];
    const float* W1     = (const float*)d_in[9];
    const float* b1     = (const float*)d_in[10];
    const float* W2     = (const float*)d_in[11];
    const float* b2     = (const float*)d_in[12];
    float* out = (float*)d_out;

    fused_kdn<<<B_, 512, 0, stream>>>(x, g_norm, Wq, Wk, Wv, bv, Wo, bo, g_post,
                                      W1, b1, W2, b2, out);
}